// Round 1
// baseline (562.575 us; speedup 1.0000x reference)
//
#include <hip/hip_runtime.h>

// Problem dims
#define NN 128
#define MM 2048
#define DXX 64
#define DYY 8
#define DUU 256
#define DZZ 256
#define EPSF 0.01f

// Workspace layout (float offsets)
#define WS_WT    0            // softplus(Wz1) transposed [z][k], 256*256
#define WS_C0    65536        // [n][z] 128*256
#define WS_GZ1   98304        // [n][z]
#define WS_C1    131072       // [n][k]
#define WS_W2    163840       // [n][k] = gz2*softplus(Wz2)
#define WS_GY0   196608       // [n][8]
#define WS_GY1   197632       // [n][8]
#define WS_YV    198656       // [n][8] = Y - gy2*Wy2
#define WS_CU2   199680       // [n]
#define WS_SLACK 199936       // [n][m] 128*2048
// total 462080 floats = 1.81 MB

__device__ __forceinline__ float softplusf(float x) {
    return x > 20.f ? x : log1pf(expf(x));
}

__device__ __forceinline__ float dot64_ls(const float* __restrict__ w, const float* s) {
    const float4* w4 = (const float4*)w;
    float a = 0.f;
#pragma unroll
    for (int q = 0; q < 16; ++q) {
        float4 v = w4[q];
        a += v.x * s[4*q] + v.y * s[4*q+1] + v.z * s[4*q+2] + v.w * s[4*q+3];
    }
    return a;
}

__device__ __forceinline__ float dot256_ls(const float* __restrict__ w, const float* s) {
    const float4* w4 = (const float4*)w;
    float a = 0.f;
#pragma unroll
    for (int q = 0; q < 64; ++q) {
        float4 v = w4[q];
        a += v.x * s[4*q] + v.y * s[4*q+1] + v.z * s[4*q+2] + v.w * s[4*q+3];
    }
    return a;
}

// ---------------------------------------------------------------------------
// Kernel 0: WT[z*256+k] = softplus(Wz1[k*256+z])
// ---------------------------------------------------------------------------
__global__ __launch_bounds__(256) void k_spT(const float* __restrict__ Wz1,
                                             float* __restrict__ WT) {
    int o = blockIdx.x * 256 + threadIdx.x;   // 65536 total
    int z = o >> 8;
    int k = o & 255;
    WT[o] = softplusf(Wz1[k * 256 + z]);
}

// ---------------------------------------------------------------------------
// Kernel 1: per-n precompute (one block per n)
// ---------------------------------------------------------------------------
__global__ __launch_bounds__(256) void k_pern(
    const float* __restrict__ X, const float* __restrict__ Y,
    const float* __restrict__ Wt0, const float* __restrict__ bt0,
    const float* __restrict__ Wt1, const float* __restrict__ bt1,
    const float* __restrict__ Wyu0, const float* __restrict__ byu0,
    const float* __restrict__ Wu0, const float* __restrict__ b0,
    const float* __restrict__ Wzu1, const float* __restrict__ bzu1,
    const float* __restrict__ Wyu1, const float* __restrict__ byu1,
    const float* __restrict__ Wu1, const float* __restrict__ b1,
    const float* __restrict__ Wzu2, const float* __restrict__ bzu2,
    const float* __restrict__ Wz2,
    const float* __restrict__ Wyu2, const float* __restrict__ byu2,
    const float* __restrict__ Wy2,
    const float* __restrict__ Wu2, const float* __restrict__ b2,
    float* __restrict__ ws)
{
    __shared__ float xs[64];
    __shared__ float u1s[256];
    __shared__ float u2s[256];
    __shared__ float red[4];
    const int n = blockIdx.x;
    const int t = threadIdx.x;

    if (t < 64) xs[t] = X[n * 64 + t];
    __syncthreads();

    // u1, c0, gy0  (all dot64 over X)
    u1s[t] = fmaxf(dot64_ls(Wt0 + t * 64, xs) + bt0[t], 0.f);
    ws[WS_C0 + n * 256 + t] = dot64_ls(Wu0 + t * 64, xs) + b0[t];
    if (t < 8) ws[WS_GY0 + n * 8 + t] = dot64_ls(Wyu0 + t * 64, xs) + byu0[t];
    __syncthreads();

    // u2, gz1, c1, gy1 (dot256 over u1)
    u2s[t] = fmaxf(dot256_ls(Wt1 + t * 256, u1s) + bt1[t], 0.f);
    ws[WS_GZ1 + n * 256 + t] = fmaxf(dot256_ls(Wzu1 + t * 256, u1s) + bzu1[t], 0.f);
    ws[WS_C1 + n * 256 + t] = dot256_ls(Wu1 + t * 256, u1s) + b1[t];
    if (t < 8) ws[WS_GY1 + n * 8 + t] = dot256_ls(Wyu1 + t * 256, u1s) + byu1[t];
    __syncthreads();

    // gz2 -> w2, gy2 -> yv, cu2 (dot256 over u2)
    {
        float gz2 = fmaxf(dot256_ls(Wzu2 + t * 256, u2s) + bzu2[t], 0.f);
        ws[WS_W2 + n * 256 + t] = gz2 * softplusf(Wz2[t]);
    }
    if (t < 8) {
        float gy2 = dot256_ls(Wyu2 + t * 256, u2s) + byu2[t];
        ws[WS_YV + n * 8 + t] = Y[n * 8 + t] - gy2 * Wy2[t];
    }
    // cu2 = u2 . Wu2 + b2
    float v = u2s[t] * Wu2[t];
#pragma unroll
    for (int off = 32; off; off >>= 1) v += __shfl_xor(v, off);
    if ((t & 63) == 0) red[t >> 6] = v;
    __syncthreads();
    if (t == 0) ws[WS_CU2 + n] = red[0] + red[1] + red[2] + red[3] + b2[0];
}

// ---------------------------------------------------------------------------
// Kernel 2: fused main — per (n, 64-m tile): build zh, GEMM vs spWz1^T,
// epilogue (relu, w2-weighted k-reduction), write slack[n][m].
// ---------------------------------------------------------------------------
#define MT 64
#define ZC 32
#define ZHP 68   // padded LDS row stride for zh[z][m]

__global__ __launch_bounds__(256, 3) void k_main(
    const float* __restrict__ U,
    const float* __restrict__ Wy0,
    const float* __restrict__ Wy1,
    float* __restrict__ ws)
{
    __shared__ float WLDS[ZC * 256];      // 32 KB: spWz1^T chunk [z_local][k]
    __shared__ float zhs[ZC * ZHP];       // 8.5 KB: zh chunk [z_local][m], padded
    __shared__ float c0s[256];
    __shared__ float gz1s[256];
    __shared__ float tym0[MT][8];         // U[m,d]*gy0[n,d]
    __shared__ float tym1[MT][8];         // U[m,d]*gy1[n,d]
    __shared__ float sdot[MT];            // U[m,:] . yv[n,:]

    const int t = threadIdx.x;
    const int n = blockIdx.y;
    const int m0g = blockIdx.x * MT;

    // ---- block-start staging ----
    c0s[t]  = ws[WS_C0  + n * 256 + t];
    gz1s[t] = ws[WS_GZ1 + n * 256 + t];
    if (t < MT) {
        int mg = m0g + t;
        float sd = 0.f;
#pragma unroll
        for (int d = 0; d < 8; ++d) {
            float u = U[mg * 8 + d];
            tym0[t][d] = u * ws[WS_GY0 + n * 8 + d];
            tym1[t][d] = u * ws[WS_GY1 + n * 8 + d];
            sd += u * ws[WS_YV + n * 8 + d];
        }
        sdot[t] = sd;
    }

    const int kb   = t & 31;   // k lane 0..31  (also reused as z_local in phase 1)
    const int mq   = t >> 5;   // m group 0..7
    const int mloc = mq * 8;

    // acc[j][i]: k = kb + 32*j, m = mloc + i; init with c1[k]
    float acc[8][8];
#pragma unroll
    for (int j = 0; j < 8; ++j) {
        float c1v = ws[WS_C1 + n * 256 + kb + 32 * j];
#pragma unroll
        for (int i = 0; i < 8; ++i) acc[j][i] = c1v;
    }
    __syncthreads();

    // ---- K loop over 8 chunks of 32 z ----
    for (int c = 0; c < 8; ++c) {
        // stage spWz1^T chunk: 32x256 floats, coalesced float4
        {
            const float4* src = (const float4*)(ws + WS_WT + c * ZC * 256);
            float4* dst = (float4*)WLDS;
#pragma unroll
            for (int q = 0; q < 8; ++q) dst[t + 256 * q] = src[t + 256 * q];
        }
        // build zh chunk: thread (z_local=kb, m group mq) does 8 m's
        {
            const int zg = c * ZC + kb;
            const float4* wy = (const float4*)(Wy0 + zg * 8);
            float4 wa = wy[0], wb = wy[1];
            float c0v = c0s[zg];
            float g1v = gz1s[zg];
#pragma unroll
            for (int i = 0; i < 8; ++i) {
                const float* ty = tym0[mloc + i];
                float s = c0v;
                s += wa.x * ty[0] + wa.y * ty[1] + wa.z * ty[2] + wa.w * ty[3];
                s += wb.x * ty[4] + wb.y * ty[5] + wb.z * ty[6] + wb.w * ty[7];
                zhs[kb * ZHP + mloc + i] = fmaxf(s, 0.f) * g1v;
            }
        }
        __syncthreads();

        // accumulate: 32 z x (8k x 8m) FMAs
#pragma unroll 2
        for (int z = 0; z < ZC; ++z) {
            float4 z0 = *(const float4*)&zhs[z * ZHP + mloc];
            float4 z1 = *(const float4*)&zhs[z * ZHP + mloc + 4];
            float zr[8] = {z0.x, z0.y, z0.z, z0.w, z1.x, z1.y, z1.z, z1.w};
            float wr[8];
#pragma unroll
            for (int j = 0; j < 8; ++j) wr[j] = WLDS[z * 256 + kb + 32 * j];
#pragma unroll
            for (int j = 0; j < 8; ++j)
#pragma unroll
                for (int i = 0; i < 8; ++i)
                    acc[j][i] += wr[j] * zr[i];
        }
        __syncthreads();
    }

    // ---- epilogue: z2 = relu(acc + U*gy1.Wy1), phi-partials, k-reduction ----
    float p[8] = {0.f, 0.f, 0.f, 0.f, 0.f, 0.f, 0.f, 0.f};
#pragma unroll
    for (int j = 0; j < 8; ++j) {
        const int k = kb + 32 * j;
        const float w2v = ws[WS_W2 + n * 256 + k];
        const float4* wy = (const float4*)(Wy1 + k * 8);
        float4 wa = wy[0], wb = wy[1];
#pragma unroll
        for (int i = 0; i < 8; ++i) {
            const float* ty = tym1[mloc + i];
            float s = acc[j][i];
            s += wa.x * ty[0] + wa.y * ty[1] + wa.z * ty[2] + wa.w * ty[3];
            s += wb.x * ty[4] + wb.y * ty[5] + wb.z * ty[6] + wb.w * ty[7];
            p[i] += fmaxf(s, 0.f) * w2v;
        }
    }
    // reduce over the 32 k-lanes (xor <=16 stays within each 32-lane half)
#pragma unroll
    for (int i = 0; i < 8; ++i) {
        float v = p[i];
        v += __shfl_xor(v, 16);
        v += __shfl_xor(v, 8);
        v += __shfl_xor(v, 4);
        v += __shfl_xor(v, 2);
        v += __shfl_xor(v, 1);
        p[i] = v;
    }
    if (kb == 0) {
        const float cu2 = ws[WS_CU2 + n];
#pragma unroll
        for (int i = 0; i < 8; ++i) {
            ws[WS_SLACK + n * 2048 + m0g + mloc + i] = sdot[mloc + i] - cu2 - p[i];
        }
    }
}

// ---------------------------------------------------------------------------
// Kernel 3: per-n stable logsumexp over m -> psi[n]
// ---------------------------------------------------------------------------
__global__ __launch_bounds__(256) void k_lse(const float* __restrict__ ws,
                                             float* __restrict__ out) {
    __shared__ float redmax[4];
    __shared__ float redsum[4];
    const int n = blockIdx.x;
    const int t = threadIdx.x;
    const float* s = ws + WS_SLACK + n * 2048;

    float vals[8];
    float mx = -3.4e38f;
#pragma unroll
    for (int i = 0; i < 8; ++i) {
        vals[i] = s[t + 256 * i];
        mx = fmaxf(mx, vals[i]);
    }
#pragma unroll
    for (int off = 32; off; off >>= 1) mx = fmaxf(mx, __shfl_xor(mx, off));
    if ((t & 63) == 0) redmax[t >> 6] = mx;
    __syncthreads();
    mx = fmaxf(fmaxf(redmax[0], redmax[1]), fmaxf(redmax[2], redmax[3]));

    float sum = 0.f;
#pragma unroll
    for (int i = 0; i < 8; ++i) sum += expf((vals[i] - mx) * (1.f / EPSF));
#pragma unroll
    for (int off = 32; off; off >>= 1) sum += __shfl_xor(sum, off);
    if ((t & 63) == 0) redsum[t >> 6] = sum;
    __syncthreads();
    if (t == 0) {
        float S = redsum[0] + redsum[1] + redsum[2] + redsum[3];
        out[n] = EPSF * logf(S * (1.f / 2048.f)) + mx;
    }
}

// ---------------------------------------------------------------------------
extern "C" void kernel_launch(void* const* d_in, const int* in_sizes, int n_in,
                              void* d_out, int out_size, void* d_ws, size_t ws_size,
                              hipStream_t stream) {
    const float* X    = (const float*)d_in[0];
    const float* Uu   = (const float*)d_in[1];
    const float* Yy   = (const float*)d_in[2];
    const float* Wt0  = (const float*)d_in[3];
    const float* bt0  = (const float*)d_in[4];
    const float* Wt1  = (const float*)d_in[5];
    const float* bt1  = (const float*)d_in[6];
    const float* Wyu0 = (const float*)d_in[7];
    const float* byu0 = (const float*)d_in[8];
    const float* Wy0  = (const float*)d_in[9];
    const float* Wu0  = (const float*)d_in[10];
    const float* b0   = (const float*)d_in[11];
    const float* Wzu1 = (const float*)d_in[12];
    const float* bzu1 = (const float*)d_in[13];
    const float* Wz1  = (const float*)d_in[14];
    const float* Wyu1 = (const float*)d_in[15];
    const float* byu1 = (const float*)d_in[16];
    const float* Wy1  = (const float*)d_in[17];
    const float* Wu1  = (const float*)d_in[18];
    const float* b1   = (const float*)d_in[19];
    const float* Wzu2 = (const float*)d_in[20];
    const float* bzu2 = (const float*)d_in[21];
    const float* Wz2  = (const float*)d_in[22];
    const float* Wyu2 = (const float*)d_in[23];
    const float* byu2 = (const float*)d_in[24];
    const float* Wy2  = (const float*)d_in[25];
    const float* Wu2  = (const float*)d_in[26];
    const float* b2   = (const float*)d_in[27];
    float* ws  = (float*)d_ws;
    float* out = (float*)d_out;

    k_spT<<<dim3(256), dim3(256), 0, stream>>>(Wz1, ws + WS_WT);
    k_pern<<<dim3(128), dim3(256), 0, stream>>>(
        X, Yy, Wt0, bt0, Wt1, bt1, Wyu0, byu0, Wu0, b0,
        Wzu1, bzu1, Wyu1, byu1, Wu1, b1,
        Wzu2, bzu2, Wz2, Wyu2, byu2, Wy2, Wu2, b2, ws);
    k_main<<<dim3(MM / MT, NN), dim3(256), 0, stream>>>(Uu, Wy0, Wy1, ws);
    k_lse<<<dim3(NN), dim3(256), 0, stream>>>(ws, out);
}

// Round 2
// 250.260 us; speedup vs baseline: 2.2480x; 2.2480x over previous
//
#include <hip/hip_runtime.h>

// Problem dims
#define NN 128
#define MM 2048
#define EPSF 0.01f

typedef __bf16 bf16x8 __attribute__((ext_vector_type(8)));
typedef __bf16 bf16x4 __attribute__((ext_vector_type(4)));
typedef float  f32x4  __attribute__((ext_vector_type(4)));

// Workspace layout (float offsets)
#define WS_SLACK 0            // [n][m] 128*2048 fp32
#define WS_W2    262144       // [n][256] fp32  gz2*softplus(Wz2)
#define WS_GZ1   294912       // [n][256] fp32
#define WS_YV    327680       // [n][8]  fp32   Y - gy2*Wy2
#define WS_CU2   328704       // [n]     fp32
#define WS_WTB   328832       // bf16 [256 k][256 z] = softplus(Wz1)   (32768 floats)
#define WS_A2    361600       // bf16 [2048 m][32]   = [U | 1 | 0...]  (32768 floats)
#define WS_B2    394368       // bf16 [128 n][256 z][32] = [gy0*Wy0 | c0 | 0...] (524288 floats)
#define WS_BX    918656       // bf16 [128 n][256 k][32] = [gy1*Wy1 | c1 | 0...] (524288 floats)
// total 1442944 floats = 5.77 MB

__device__ __forceinline__ float softplusf(float x) {
    return x > 20.f ? x : log1pf(expf(x));
}

__device__ __forceinline__ float dot64_ls(const float* __restrict__ w, const float* s) {
    const float4* w4 = (const float4*)w;
    float a = 0.f;
#pragma unroll
    for (int q = 0; q < 16; ++q) {
        float4 v = w4[q];
        a += v.x * s[4*q] + v.y * s[4*q+1] + v.z * s[4*q+2] + v.w * s[4*q+3];
    }
    return a;
}

__device__ __forceinline__ float dot256_ls(const float* __restrict__ w, const float* s) {
    const float4* w4 = (const float4*)w;
    float a = 0.f;
#pragma unroll
    for (int q = 0; q < 64; ++q) {
        float4 v = w4[q];
        a += v.x * s[4*q] + v.y * s[4*q+1] + v.z * s[4*q+2] + v.w * s[4*q+3];
    }
    return a;
}

// ---------------------------------------------------------------------------
// Kernel 0: one-time prep — WTb = bf16(softplus(Wz1)) [k][z]; A2 = [U | 1 | 0]
// ---------------------------------------------------------------------------
__global__ __launch_bounds__(256) void k_prep(const float* __restrict__ Wz1,
                                              const float* __restrict__ U,
                                              float* __restrict__ ws) {
    int i = blockIdx.x * 256 + threadIdx.x;   // 131072 total
    if (i < 65536) {
        ((__bf16*)(ws + WS_WTB))[i] = (__bf16)softplusf(Wz1[i]);
    } else {
        int o = i - 65536;
        int m = o >> 5, cc = o & 31;
        float v = cc < 8 ? U[m * 8 + cc] : (cc == 8 ? 1.f : 0.f);
        ((__bf16*)(ws + WS_A2))[o] = (__bf16)v;
    }
}

// ---------------------------------------------------------------------------
// Kernel 1: per-n precompute (one block per n)
// ---------------------------------------------------------------------------
__global__ __launch_bounds__(256) void k_pern(
    const float* __restrict__ X, const float* __restrict__ Y,
    const float* __restrict__ Wt0, const float* __restrict__ bt0,
    const float* __restrict__ Wt1, const float* __restrict__ bt1,
    const float* __restrict__ Wyu0, const float* __restrict__ byu0,
    const float* __restrict__ Wy0,
    const float* __restrict__ Wu0, const float* __restrict__ b0,
    const float* __restrict__ Wzu1, const float* __restrict__ bzu1,
    const float* __restrict__ Wyu1, const float* __restrict__ byu1,
    const float* __restrict__ Wy1,
    const float* __restrict__ Wu1, const float* __restrict__ b1,
    const float* __restrict__ Wzu2, const float* __restrict__ bzu2,
    const float* __restrict__ Wz2,
    const float* __restrict__ Wyu2, const float* __restrict__ byu2,
    const float* __restrict__ Wy2,
    const float* __restrict__ Wu2, const float* __restrict__ b2,
    float* __restrict__ ws)
{
    __shared__ float xs[64];
    __shared__ float u1s[256];
    __shared__ float u2s[256];
    __shared__ float gy0s[8];
    __shared__ float gy1s[8];
    __shared__ float red[4];
    const int n = blockIdx.x;
    const int t = threadIdx.x;

    if (t < 64) xs[t] = X[n * 64 + t];
    __syncthreads();

    // u1, c0, gy0 (dot64 over X)
    u1s[t] = fmaxf(dot64_ls(Wt0 + t * 64, xs) + bt0[t], 0.f);
    float c0 = dot64_ls(Wu0 + t * 64, xs) + b0[t];
    if (t < 8) gy0s[t] = dot64_ls(Wyu0 + t * 64, xs) + byu0[t];
    __syncthreads();

    // B2 row t (z = t): [gy0*Wy0 | c0 | 0...]
    {
        __bf16* B2 = (__bf16*)(ws + WS_B2) + n * 8192 + t * 32;
#pragma unroll
        for (int d = 0; d < 8; ++d) B2[d] = (__bf16)(gy0s[d] * Wy0[t * 8 + d]);
        B2[8] = (__bf16)c0;
#pragma unroll
        for (int j = 9; j < 32; ++j) B2[j] = (__bf16)0.f;
    }

    // u2, gz1, c1, gy1 (dot256 over u1)
    u2s[t] = fmaxf(dot256_ls(Wt1 + t * 256, u1s) + bt1[t], 0.f);
    ws[WS_GZ1 + n * 256 + t] = fmaxf(dot256_ls(Wzu1 + t * 256, u1s) + bzu1[t], 0.f);
    float c1 = dot256_ls(Wu1 + t * 256, u1s) + b1[t];
    if (t < 8) gy1s[t] = dot256_ls(Wyu1 + t * 256, u1s) + byu1[t];
    __syncthreads();

    // Bx row t (k = t): [gy1*Wy1 | c1 | 0...]
    {
        __bf16* Bx = (__bf16*)(ws + WS_BX) + n * 8192 + t * 32;
#pragma unroll
        for (int d = 0; d < 8; ++d) Bx[d] = (__bf16)(gy1s[d] * Wy1[t * 8 + d]);
        Bx[8] = (__bf16)c1;
#pragma unroll
        for (int j = 9; j < 32; ++j) Bx[j] = (__bf16)0.f;
    }

    // gz2 -> w2, gy2 -> yv, cu2 (dot256 over u2)
    {
        float gz2 = fmaxf(dot256_ls(Wzu2 + t * 256, u2s) + bzu2[t], 0.f);
        ws[WS_W2 + n * 256 + t] = gz2 * softplusf(Wz2[t]);
    }
    if (t < 8) {
        float gy2 = dot256_ls(Wyu2 + t * 256, u2s) + byu2[t];
        ws[WS_YV + n * 8 + t] = Y[n * 8 + t] - gy2 * Wy2[t];
    }
    float v = u2s[t] * Wu2[t];
#pragma unroll
    for (int off = 32; off; off >>= 1) v += __shfl_xor(v, off);
    if ((t & 63) == 0) red[t >> 6] = v;
    __syncthreads();
    if (t == 0) ws[WS_CU2 + n] = red[0] + red[1] + red[2] + red[3] + b2[0];
}

// ---------------------------------------------------------------------------
// Kernel 2: MFMA main — per (n, 64-m tile):
//   pre-GEMM (K=32): pre^T[z][m] = B2[z,:]·A2[m,:]  -> relu*gz1 -> zh LDS (bf16)
//   main GEMM: z2pre[m][k] = zh[m,:]·WTb[k,:] + A2[m,:]·Bx[k,:]  (9 K-chunks)
//   epilogue: p[m] = sum_k relu(z2pre)*w2[k]; slack = sdot - cu2 - p
// ---------------------------------------------------------------------------
__global__ __launch_bounds__(256, 3) void k_main(
    const float* __restrict__ U,
    float* __restrict__ ws)
{
    __shared__ __bf16 zh[64][264];   // 33792 B, +8 pad: 2-way (free) b128 reads
    __shared__ float gz1s[256];
    __shared__ float w2s[256];
    __shared__ float sdot[64];
    __shared__ float psum[4][64];

    const int t  = threadIdx.x;
    const int n  = blockIdx.y;
    const int m0 = blockIdx.x * 64;
    const int w    = t >> 6;
    const int lane = t & 63;
    const int c = lane & 15;   // MFMA row/col lane index
    const int q = lane >> 4;   // quad

    gz1s[t] = ws[WS_GZ1 + n * 256 + t];
    w2s[t]  = ws[WS_W2  + n * 256 + t];
    if (t < 64) {
        float sd = 0.f;
#pragma unroll
        for (int d = 0; d < 8; ++d)
            sd += U[(m0 + t) * 8 + d] * ws[WS_YV + n * 8 + d];
        sdot[t] = sd;
    }

    const __bf16* A2p = (const __bf16*)(ws + WS_A2);
    const __bf16* B2p = (const __bf16*)(ws + WS_B2) + n * 8192;
    const __bf16* BXp = (const __bf16*)(ws + WS_BX) + n * 8192;
    const __bf16* WTp = (const __bf16*)(ws + WS_WTB);

    // A2 fragments: A2[m = c+16mi][kk = q*8+j] — used as B-operand in pre-GEMM
    // and as A-operand in main-GEMM chunk 9 (identical lane layout).
    bf16x8 a2f[4];
#pragma unroll
    for (int mi = 0; mi < 4; ++mi)
        a2f[mi] = *(const bf16x8*)(A2p + (m0 + 16 * mi + c) * 32 + q * 8);

    // ---- pre-GEMM: D1[z][m], wave w covers z in [64w, 64w+64) ----
    {
        bf16x8 b2f[4];
#pragma unroll
        for (int zt = 0; zt < 4; ++zt)
            b2f[zt] = *(const bf16x8*)(B2p + (64 * w + 16 * zt + c) * 32 + q * 8);
        f32x4 pre[4][4];
#pragma unroll
        for (int zt = 0; zt < 4; ++zt)
#pragma unroll
            for (int mi = 0; mi < 4; ++mi) {
                f32x4 zeroacc = {0.f, 0.f, 0.f, 0.f};
                pre[zt][mi] = __builtin_amdgcn_mfma_f32_16x16x32_bf16(
                    b2f[zt], a2f[mi], zeroacc, 0, 0, 0);
            }
        // relu * gz1, cvt, write 4 consecutive z per lane (b64)
#pragma unroll
        for (int zt = 0; zt < 4; ++zt) {
            const int zb = 64 * w + 16 * zt + 4 * q;
#pragma unroll
            for (int mi = 0; mi < 4; ++mi) {
                bf16x4 v4;
#pragma unroll
                for (int r = 0; r < 4; ++r)
                    v4[r] = (__bf16)(fmaxf(pre[zt][mi][r], 0.f) * gz1s[zb + r]);
                *(bf16x4*)&zh[c + 16 * mi][zb] = v4;
            }
        }
    }

    // ---- main GEMM: D2[m][k], wave w covers k in [64w, 64w+64) ----
    f32x4 acc[4][4];
#pragma unroll
    for (int mi = 0; mi < 4; ++mi)
#pragma unroll
        for (int kj = 0; kj < 4; ++kj)
            acc[mi][kj] = f32x4{0.f, 0.f, 0.f, 0.f};

    __syncthreads();

    for (int ch = 0; ch < 8; ++ch) {
        bf16x8 az[4], bw[4];
#pragma unroll
        for (int mi = 0; mi < 4; ++mi)
            az[mi] = *(const bf16x8*)&zh[c + 16 * mi][ch * 32 + q * 8];
#pragma unroll
        for (int kj = 0; kj < 4; ++kj)
            bw[kj] = *(const bf16x8*)(WTp + (64 * w + 16 * kj + c) * 256 + ch * 32 + q * 8);
#pragma unroll
        for (int mi = 0; mi < 4; ++mi)
#pragma unroll
            for (int kj = 0; kj < 4; ++kj)
                acc[mi][kj] = __builtin_amdgcn_mfma_f32_16x16x32_bf16(
                    az[mi], bw[kj], acc[mi][kj], 0, 0, 0);
    }
    // chunk 9: Wy1 term + c1 via [U | 1] x [gy1*Wy1 | c1]
    {
        bf16x8 bx[4];
#pragma unroll
        for (int kj = 0; kj < 4; ++kj)
            bx[kj] = *(const bf16x8*)(BXp + (64 * w + 16 * kj + c) * 32 + q * 8);
#pragma unroll
        for (int mi = 0; mi < 4; ++mi)
#pragma unroll
            for (int kj = 0; kj < 4; ++kj)
                acc[mi][kj] = __builtin_amdgcn_mfma_f32_16x16x32_bf16(
                    a2f[mi], bx[kj], acc[mi][kj], 0, 0, 0);
    }

    // ---- epilogue: p[m] = sum_k relu(z2pre)*w2 ----
    float p[4][4];   // [mi][r]
#pragma unroll
    for (int mi = 0; mi < 4; ++mi)
#pragma unroll
        for (int r = 0; r < 4; ++r) p[mi][r] = 0.f;
#pragma unroll
    for (int kj = 0; kj < 4; ++kj) {
        float w2v = w2s[64 * w + 16 * kj + c];
#pragma unroll
        for (int mi = 0; mi < 4; ++mi)
#pragma unroll
            for (int r = 0; r < 4; ++r)
                p[mi][r] += fmaxf(acc[mi][kj][r], 0.f) * w2v;
    }
    // reduce over the 16 c-lanes
#pragma unroll
    for (int mi = 0; mi < 4; ++mi)
#pragma unroll
        for (int r = 0; r < 4; ++r) {
            float v = p[mi][r];
            v += __shfl_xor(v, 8);
            v += __shfl_xor(v, 4);
            v += __shfl_xor(v, 2);
            v += __shfl_xor(v, 1);
            p[mi][r] = v;
        }
    if (c == 0) {
#pragma unroll
        for (int mi = 0; mi < 4; ++mi) {
            float4 v = make_float4(p[mi][0], p[mi][1], p[mi][2], p[mi][3]);
            *(float4*)&psum[w][16 * mi + 4 * q] = v;
        }
    }
    __syncthreads();
    if (t < 64) {
        float cu2 = ws[WS_CU2 + n];
        float pp = psum[0][t] + psum[1][t] + psum[2][t] + psum[3][t];
        ws[WS_SLACK + n * 2048 + m0 + t] = sdot[t] - cu2 - pp;
    }
}

// ---------------------------------------------------------------------------
// Kernel 3: per-n stable logsumexp over m -> psi[n]
// ---------------------------------------------------------------------------
__global__ __launch_bounds__(256) void k_lse(const float* __restrict__ ws,
                                             float* __restrict__ out) {
    __shared__ float redmax[4];
    __shared__ float redsum[4];
    const int n = blockIdx.x;
    const int t = threadIdx.x;
    const float* s = ws + WS_SLACK + n * 2048;

    float vals[8];
    float mx = -3.4e38f;
#pragma unroll
    for (int i = 0; i < 8; ++i) {
        vals[i] = s[t + 256 * i];
        mx = fmaxf(mx, vals[i]);
    }
#pragma unroll
    for (int off = 32; off; off >>= 1) mx = fmaxf(mx, __shfl_xor(mx, off));
    if ((t & 63) == 0) redmax[t >> 6] = mx;
    __syncthreads();
    mx = fmaxf(fmaxf(redmax[0], redmax[1]), fmaxf(redmax[2], redmax[3]));

    float sum = 0.f;
#pragma unroll
    for (int i = 0; i < 8; ++i) sum += expf((vals[i] - mx) * (1.f / EPSF));
#pragma unroll
    for (int off = 32; off; off >>= 1) sum += __shfl_xor(sum, off);
    if ((t & 63) == 0) redsum[t >> 6] = sum;
    __syncthreads();
    if (t == 0) {
        float S = redsum[0] + redsum[1] + redsum[2] + redsum[3];
        out[n] = EPSF * logf(S * (1.f / 2048.f)) + mx;
    }
}

// ---------------------------------------------------------------------------
extern "C" void kernel_launch(void* const* d_in, const int* in_sizes, int n_in,
                              void* d_out, int out_size, void* d_ws, size_t ws_size,
                              hipStream_t stream) {
    const float* X    = (const float*)d_in[0];
    const float* Uu   = (const float*)d_in[1];
    const float* Yy   = (const float*)d_in[2];
    const float* Wt0  = (const float*)d_in[3];
    const float* bt0  = (const float*)d_in[4];
    const float* Wt1  = (const float*)d_in[5];
    const float* bt1  = (const float*)d_in[6];
    const float* Wyu0 = (const float*)d_in[7];
    const float* byu0 = (const float*)d_in[8];
    const float* Wy0  = (const float*)d_in[9];
    const float* Wu0  = (const float*)d_in[10];
    const float* b0   = (const float*)d_in[11];
    const float* Wzu1 = (const float*)d_in[12];
    const float* bzu1 = (const float*)d_in[13];
    const float* Wz1  = (const float*)d_in[14];
    const float* Wyu1 = (const float*)d_in[15];
    const float* byu1 = (const float*)d_in[16];
    const float* Wy1  = (const float*)d_in[17];
    const float* Wu1  = (const float*)d_in[18];
    const float* b1   = (const float*)d_in[19];
    const float* Wzu2 = (const float*)d_in[20];
    const float* bzu2 = (const float*)d_in[21];
    const float* Wz2  = (const float*)d_in[22];
    const float* Wyu2 = (const float*)d_in[23];
    const float* byu2 = (const float*)d_in[24];
    const float* Wy2  = (const float*)d_in[25];
    const float* Wu2  = (const float*)d_in[26];
    const float* b2   = (const float*)d_in[27];
    float* ws  = (float*)d_ws;
    float* out = (float*)d_out;

    k_prep<<<dim3(512), dim3(256), 0, stream>>>(Wz1, Uu, ws);
    k_pern<<<dim3(128), dim3(256), 0, stream>>>(
        X, Yy, Wt0, bt0, Wt1, bt1, Wyu0, byu0, Wy0, Wu0, b0,
        Wzu1, bzu1, Wyu1, byu1, Wy1, Wu1, b1,
        Wzu2, bzu2, Wz2, Wyu2, byu2, Wy2, Wu2, b2, ws);
    k_main<<<dim3(MM / 64, NN), dim3(256), 0, stream>>>(Uu, ws);
    k_lse<<<dim3(NN), dim3(256), 0, stream>>>(ws, out);
}